// Round 3
// baseline (453.952 us; speedup 1.0000x reference)
//
#include <hip/hip_runtime.h>
#include <hip/hip_bf16.h>

#define NROWS 16384
#define DIM   256
#define SEGS  16
#define BN    64
#define INVT  14.285714285714286f
#define C1f   20.60992915555662f   // log2(e)/0.07 ; A is pre-scaled by this
#define LN2f  0.6931471805599453f

typedef __attribute__((ext_vector_type(8)))  short short8;   // 8 x bf16 (4 VGPRs)
typedef __attribute__((ext_vector_type(16))) float f32x16;   // 32x32 MFMA accumulator

__device__ __forceinline__ unsigned short f2bf(float x) {
    union { float f; unsigned int u; } v; v.f = x;
    unsigned int r = v.u + 0x7fffu + ((v.u >> 16) & 1u);    // RNE; inputs are finite
    return (unsigned short)(r >> 16);
}

// Kernel 1: L2-normalize both feature sets (fp32); emit bf16 A (scaled by C1) and
// bf16 B (unscaled), plus the exact fp32 diagonal. One wave per row.
__global__ __launch_bounds__(256) void norm_diag_kernel(
    const float* __restrict__ fl, const float* __restrict__ fg,
    unsigned short* __restrict__ A, unsigned short* __restrict__ B,
    float* __restrict__ diag, float* __restrict__ out)
{
    int tid  = threadIdx.x;
    int wave = tid >> 6, lane = tid & 63;
    int row  = blockIdx.x * 4 + wave;
    if (blockIdx.x == 0 && tid == 0) out[0] = 0.0f;   // zero accumulator for final atomicAdd

    float4 xl = ((const float4*)(fl + (size_t)row * DIM))[lane];
    float4 xg = ((const float4*)(fg + (size_t)row * DIM))[lane];
    float ssl = xl.x*xl.x + xl.y*xl.y + xl.z*xl.z + xl.w*xl.w;
    float ssg = xg.x*xg.x + xg.y*xg.y + xg.z*xg.z + xg.w*xg.w;
    for (int m = 1; m < 64; m <<= 1) {
        ssl += __shfl_xor(ssl, m, 64);
        ssg += __shfl_xor(ssg, m, 64);
    }
    float il = 1.0f / fmaxf(sqrtf(ssl), 1e-12f);
    float ig = 1.0f / fmaxf(sqrtf(ssg), 1e-12f);
    float nl0 = xl.x*il, nl1 = xl.y*il, nl2 = xl.z*il, nl3 = xl.w*il;
    float ng0 = xg.x*ig, ng1 = xg.y*ig, ng2 = xg.z*ig, ng3 = xg.w*ig;

    ushort4 pa, pb;
    pa.x = f2bf(nl0 * C1f); pa.y = f2bf(nl1 * C1f); pa.z = f2bf(nl2 * C1f); pa.w = f2bf(nl3 * C1f);
    pb.x = f2bf(ng0); pb.y = f2bf(ng1); pb.z = f2bf(ng2); pb.w = f2bf(ng3);
    ((ushort4*)(A + (size_t)row * DIM))[lane] = pa;
    ((ushort4*)(B + (size_t)row * DIM))[lane] = pb;

    float d = nl0*ng0 + nl1*ng1 + nl2*ng2 + nl3*ng3;   // exact fp32 diagonal (unscaled)
    for (int m = 1; m < 64; m <<= 1) d += __shfl_xor(d, m, 64);
    if (lane == 0) diag[row] = d;
}

// Kernel 2: fused sim-tile GEMM + fixed-max sumexp, 32x32x16 MFMA.
// Block = 4 waves = 256 rows; wave tile = 64 rows x 64 cols (2 row-sets x 2 col-sets of 32x32).
// A frags register-resident across all K; B tile staged in XOR-swizzled LDS.
// acc = C1*dot directly (A pre-scaled), so epilogue is exp2 + add only.
// grid = (SEGS=16, NROWS/256) = 1024 blocks -> 4 blocks/CU (vs 2 before).
__global__ __launch_bounds__(256, 4) void sim_lse_kernel(
    const unsigned short* __restrict__ A, const unsigned short* __restrict__ B,
    float* __restrict__ lpart)
{
    __shared__ unsigned short bt[BN * DIM];   // 32 KB, 16B-chunk swizzled: phys = col*32 + (kc ^ (col&7))

    int tid  = threadIdx.x;
    int wave = tid >> 6, lane = tid & 63;
    int l31  = lane & 31, half = lane >> 5;
    int rowBase = blockIdx.y * 256 + wave * 64;

    // Preload A fragments for 32x32x16: A[m=lane&31][k=half*8+j], 2 row-sets x 16 K-steps (128 VGPRs)
    short8 af[2][16];
#pragma unroll
    for (int s = 0; s < 2; ++s) {
        const unsigned short* ap = A + (size_t)(rowBase + s*32 + l31) * DIM + half*8;
#pragma unroll
        for (int kk = 0; kk < 16; ++kk)
            af[s][kk] = *(const short8*)(ap + kk*16);
    }

    float l[2][16];
#pragma unroll
    for (int s = 0; s < 2; ++s)
#pragma unroll
        for (int r = 0; r < 16; ++r) l[s][r] = 0.0f;

    int col0seg = blockIdx.x * (NROWS / SEGS);

    for (int t = 0; t < (NROWS / SEGS) / BN; ++t) {   // 16 column tiles of 64
        int col0 = col0seg + t * BN;
        __syncthreads();
        // Stage B tile (64 cols x 256 k, bf16) into swizzled LDS; 2048 16B chunks / 256 thr
#pragma unroll
        for (int i = tid; i < BN * 32; i += 256) {
            int col = i >> 5, kc = i & 31;
            int phys = col * 32 + (kc ^ (col & 7));
            *(short8*)&bt[phys * 8] = *(const short8*)(B + (size_t)(col0 + col) * DIM + kc * 8);
        }
        __syncthreads();

        f32x16 acc[2][2];
#pragma unroll
        for (int s = 0; s < 2; ++s)
#pragma unroll
            for (int c = 0; c < 2; ++c)
#pragma unroll
                for (int i = 0; i < 16; ++i) acc[s][c][i] = 0.0f;

#pragma unroll
        for (int kk = 0; kk < 16; ++kk) {
            short8 bf[2];
#pragma unroll
            for (int c = 0; c < 2; ++c) {
                int col = c * 32 + l31;
                int kc  = kk * 2 + half;              // 16B chunk index along K
                int phys = col * 32 + (kc ^ (col & 7));
                bf[c] = *(const short8*)&bt[phys * 8];
            }
#pragma unroll
            for (int c = 0; c < 2; ++c) {
                acc[0][c] = __builtin_amdgcn_mfma_f32_32x32x16_bf16(af[0][kk], bf[c], acc[0][c], 0, 0, 0);
                acc[1][c] = __builtin_amdgcn_mfma_f32_32x32x16_bf16(af[1][kk], bf[c], acc[1][c], 0, 0, 0);
            }
        }

        // Epilogue: acc already = C1*dot; sum exp2. C/D: col=lane&31, row=(r&3)+8*(r>>2)+4*half
#pragma unroll
        for (int s = 0; s < 2; ++s)
#pragma unroll
            for (int c = 0; c < 2; ++c)
#pragma unroll
                for (int r = 0; r < 16; ++r)
                    l[s][r] += __builtin_amdgcn_exp2f(acc[s][c][r]);
    }

    // Sum across the 32 column-lanes (xor 1..16 stays within each 32-half)
#pragma unroll
    for (int s = 0; s < 2; ++s)
#pragma unroll
        for (int r = 0; r < 16; ++r) {
            float v = l[s][r];
            v += __shfl_xor(v, 1, 64);
            v += __shfl_xor(v, 2, 64);
            v += __shfl_xor(v, 4, 64);
            v += __shfl_xor(v, 8, 64);
            v += __shfl_xor(v, 16, 64);
            l[s][r] = v;
        }
    if (l31 == 0) {
#pragma unroll
        for (int s = 0; s < 2; ++s)
#pragma unroll
            for (int r = 0; r < 16; ++r) {
                int row = rowBase + s*32 + (r & 3) + 8*(r >> 2) + 4*half;
                lpart[(size_t)blockIdx.x * NROWS + row] = l[s][r];
            }
    }
}

// Kernel 3: loss_i = -invT*diag_i + ln2*log2(sum_seg l_part), then mean via atomicAdd.
__global__ __launch_bounds__(256) void reduce_kernel(
    const float* __restrict__ lpart, const float* __restrict__ diag,
    float* __restrict__ out)
{
    __shared__ float sm[4];
    int gtid = blockIdx.x * 256 + threadIdx.x;
    float s = 0.0f;
    for (int row = gtid; row < NROWS; row += 32 * 256) {
        float t = 0.0f;
#pragma unroll
        for (int g = 0; g < SEGS; ++g) t += lpart[(size_t)g * NROWS + row];
        s += LN2f * log2f(t) - INVT * diag[row];
    }
    for (int m = 1; m < 64; m <<= 1) s += __shfl_xor(s, m, 64);
    int wave = threadIdx.x >> 6, lane = threadIdx.x & 63;
    if (lane == 0) sm[wave] = s;
    __syncthreads();
    if (threadIdx.x == 0) {
        float tot = sm[0] + sm[1] + sm[2] + sm[3];
        atomicAdd(out, tot * (1.0f / NROWS));
    }
}

extern "C" void kernel_launch(void* const* d_in, const int* in_sizes, int n_in,
                              void* d_out, int out_size, void* d_ws, size_t ws_size,
                              hipStream_t stream) {
    const float* fl = (const float*)d_in[0];
    const float* fg = (const float*)d_in[1];
    float* out = (float*)d_out;

    char* ws = (char*)d_ws;
    unsigned short* A = (unsigned short*)ws;                       // 16384*256*2 = 8 MB
    unsigned short* B = A + (size_t)NROWS * DIM;                   // 8 MB
    float* diag  = (float*)(ws + 2 * (size_t)NROWS * DIM * 2);     // 64 KB
    float* lpart = diag + NROWS;                                   // SEGS*N*4 = 1 MB

    norm_diag_kernel<<<NROWS / 4, 256, 0, stream>>>(fl, fg, A, B, diag, out);
    sim_lse_kernel<<<dim3(SEGS, NROWS / 256), 256, 0, stream>>>(A, B, lpart);
    reduce_kernel<<<32, 256, 0, stream>>>(lpart, diag, out);
}

// Round 4
// 214.810 us; speedup vs baseline: 2.1133x; 2.1133x over previous
//
#include <hip/hip_runtime.h>
#include <hip/hip_bf16.h>

#define NROWS 16384
#define DIM   256
#define SEGS  8
#define BN    64
#define NT    ((NROWS / SEGS) / BN)   // 32 column tiles per block
#define INVT  14.285714285714286f
#define C1f   20.60992915555662f   // log2(e)/0.07 ; A is pre-scaled by this
#define LN2f  0.6931471805599453f

typedef __attribute__((ext_vector_type(8)))  short short8;   // 8 x bf16 (4 VGPRs)
typedef __attribute__((ext_vector_type(16))) float f32x16;   // 32x32 MFMA accumulator

__device__ __forceinline__ unsigned short f2bf(float x) {
    union { float f; unsigned int u; } v; v.f = x;
    unsigned int r = v.u + 0x7fffu + ((v.u >> 16) & 1u);    // RNE; inputs are finite
    return (unsigned short)(r >> 16);
}

// Kernel 1: L2-normalize both feature sets (fp32); emit bf16 A (scaled by C1) and
// bf16 B (unscaled), plus the exact fp32 diagonal. One wave per row.
__global__ __launch_bounds__(256) void norm_diag_kernel(
    const float* __restrict__ fl, const float* __restrict__ fg,
    unsigned short* __restrict__ A, unsigned short* __restrict__ B,
    float* __restrict__ diag, float* __restrict__ out)
{
    int tid  = threadIdx.x;
    int wave = tid >> 6, lane = tid & 63;
    int row  = blockIdx.x * 4 + wave;
    if (blockIdx.x == 0 && tid == 0) out[0] = 0.0f;   // zero accumulator for final atomicAdd

    float4 xl = ((const float4*)(fl + (size_t)row * DIM))[lane];
    float4 xg = ((const float4*)(fg + (size_t)row * DIM))[lane];
    float ssl = xl.x*xl.x + xl.y*xl.y + xl.z*xl.z + xl.w*xl.w;
    float ssg = xg.x*xg.x + xg.y*xg.y + xg.z*xg.z + xg.w*xg.w;
    for (int m = 1; m < 64; m <<= 1) {
        ssl += __shfl_xor(ssl, m, 64);
        ssg += __shfl_xor(ssg, m, 64);
    }
    float il = 1.0f / fmaxf(sqrtf(ssl), 1e-12f);
    float ig = 1.0f / fmaxf(sqrtf(ssg), 1e-12f);
    float nl0 = xl.x*il, nl1 = xl.y*il, nl2 = xl.z*il, nl3 = xl.w*il;
    float ng0 = xg.x*ig, ng1 = xg.y*ig, ng2 = xg.z*ig, ng3 = xg.w*ig;

    ushort4 pa, pb;
    pa.x = f2bf(nl0 * C1f); pa.y = f2bf(nl1 * C1f); pa.z = f2bf(nl2 * C1f); pa.w = f2bf(nl3 * C1f);
    pb.x = f2bf(ng0); pb.y = f2bf(ng1); pb.z = f2bf(ng2); pb.w = f2bf(ng3);
    ((ushort4*)(A + (size_t)row * DIM))[lane] = pa;
    ((ushort4*)(B + (size_t)row * DIM))[lane] = pb;

    float d = nl0*ng0 + nl1*ng1 + nl2*ng2 + nl3*ng3;   // exact fp32 diagonal (unscaled)
    for (int m = 1; m < 64; m <<= 1) d += __shfl_xor(d, m, 64);
    if (lane == 0) diag[row] = d;
}

// Kernel 2: fused sim-tile GEMM + fixed-max sumexp, 32x32x16 MFMA (layout HW-verified R3).
// Block = 4 waves = 256 rows; wave tile = 64 rows x 64 cols (2 row-sets x 2 col-sets).
// A frags register-resident across all K. B tile double-buffered in LDS:
//   loads for tile t+1 issued AFTER the barrier (not drained by vmcnt(0)@barrier),
//   ds_write consumes them at the next iteration top (a full tile of compute later).
// LDS layout: 16B chunk (col,kc) -> phys = kc*64 + (col ^ (kc&7));
//   reads = contiguous lane-permuted 512B (stride-1-like, ~0 conflicts),
//   writes = uniform 8 lanes/bank-quad (minimum phases).
__global__ __launch_bounds__(256, 2) void sim_lse_kernel(
    const unsigned short* __restrict__ A, const unsigned short* __restrict__ B,
    float* __restrict__ lpart)
{
    __shared__ unsigned short bt[2 * BN * DIM];   // 2 x 32 KB double buffer

    int tid  = threadIdx.x;
    int lane = tid & 63;
    int l31  = lane & 31, half = lane >> 5;
    int wave = tid >> 6;
    int rowBase = blockIdx.y * 256 + wave * 64;

    // Staging assignment (fixed per thread): chunk j*256+tid -> col=(..)>>5, kc=(..)&31
    int scol[8], skc[8];
    unsigned sphys[8];
#pragma unroll
    for (int j = 0; j < 8; ++j) {
        int i = tid + j * 256;
        scol[j] = i >> 5;
        skc[j]  = i & 31;
        sphys[j] = (unsigned)(skc[j] * 64 + (scol[j] ^ (skc[j] & 7)));
    }

    // Preload A fragments for 32x32x16: lane(l31,half) holds A[m=l31][k=kk*16+half*8+j]
    short8 af[2][16];
#pragma unroll
    for (int s = 0; s < 2; ++s) {
        const unsigned short* ap = A + (size_t)(rowBase + s*32 + l31) * DIM + half*8;
#pragma unroll
        for (int kk = 0; kk < 16; ++kk)
            af[s][kk] = *(const short8*)(ap + kk*16);
    }

    float l[2][16];
#pragma unroll
    for (int s = 0; s < 2; ++s)
#pragma unroll
        for (int r = 0; r < 16; ++r) l[s][r] = 0.0f;

    int col0seg = blockIdx.x * (NROWS / SEGS);

    // Prefetch tile 0 into registers
    short8 stg[8];
#pragma unroll
    for (int j = 0; j < 8; ++j)
        stg[j] = *(const short8*)(B + (size_t)(col0seg + scol[j]) * DIM + skc[j] * 8);

    for (int t = 0; t < NT; ++t) {
        unsigned bufo = (t & 1) ? (unsigned)(BN * DIM) : 0u;
        // Commit staged registers for tile t (compiler waits vmcnt here; loads are long done)
#pragma unroll
        for (int j = 0; j < 8; ++j)
            *(short8*)&bt[bufo + sphys[j] * 8] = stg[j];
        __syncthreads();

        // Issue loads for tile t+1 AFTER the barrier so they stay in flight through compute
        if (t + 1 < NT) {
            int col0n = col0seg + (t + 1) * BN;
#pragma unroll
            for (int j = 0; j < 8; ++j)
                stg[j] = *(const short8*)(B + (size_t)(col0n + scol[j]) * DIM + skc[j] * 8);
        }

        f32x16 acc[2][2];
#pragma unroll
        for (int s = 0; s < 2; ++s)
#pragma unroll
            for (int c = 0; c < 2; ++c)
#pragma unroll
                for (int i = 0; i < 16; ++i) acc[s][c][i] = 0.0f;

#pragma unroll
        for (int kk = 0; kk < 16; ++kk) {
            short8 bf[2];
#pragma unroll
            for (int c = 0; c < 2; ++c) {
                int kc  = kk * 2 + half;                         // 16B chunk along K
                int col = c * 32 + l31;
                unsigned phys = (unsigned)(kc * 64 + (col ^ (kc & 7)));
                bf[c] = *(const short8*)&bt[bufo + phys * 8];
            }
#pragma unroll
            for (int c = 0; c < 2; ++c) {
                acc[0][c] = __builtin_amdgcn_mfma_f32_32x32x16_bf16(af[0][kk], bf[c], acc[0][c], 0, 0, 0);
                acc[1][c] = __builtin_amdgcn_mfma_f32_32x32x16_bf16(af[1][kk], bf[c], acc[1][c], 0, 0, 0);
            }
        }
        __syncthreads();   // all waves done reading buf[t&1] before it's overwritten at t+2

        // Epilogue: acc already = C1*dot; sum exp2. C/D: col=lane&31, row=(r&3)+8*(r>>2)+4*half
#pragma unroll
        for (int s = 0; s < 2; ++s)
#pragma unroll
            for (int c = 0; c < 2; ++c)
#pragma unroll
                for (int r = 0; r < 16; ++r)
                    l[s][r] += __builtin_amdgcn_exp2f(acc[s][c][r]);
    }

    // Sum across the 32 column-lanes
#pragma unroll
    for (int s = 0; s < 2; ++s)
#pragma unroll
        for (int r = 0; r < 16; ++r) {
            float v = l[s][r];
            v += __shfl_xor(v, 1, 64);
            v += __shfl_xor(v, 2, 64);
            v += __shfl_xor(v, 4, 64);
            v += __shfl_xor(v, 8, 64);
            v += __shfl_xor(v, 16, 64);
            l[s][r] = v;
        }
    if (l31 == 0) {
#pragma unroll
        for (int s = 0; s < 2; ++s)
#pragma unroll
            for (int r = 0; r < 16; ++r) {
                int row = rowBase + s*32 + (r & 3) + 8*(r >> 2) + 4*half;
                lpart[(size_t)blockIdx.x * NROWS + row] = l[s][r];
            }
    }
}

// Kernel 3: loss_i = -invT*diag_i + ln2*log2(sum_seg l_part), then mean via atomicAdd.
__global__ __launch_bounds__(256) void reduce_kernel(
    const float* __restrict__ lpart, const float* __restrict__ diag,
    float* __restrict__ out)
{
    __shared__ float sm[4];
    int gtid = blockIdx.x * 256 + threadIdx.x;
    float s = 0.0f;
    for (int row = gtid; row < NROWS; row += 32 * 256) {
        float t = 0.0f;
#pragma unroll
        for (int g = 0; g < SEGS; ++g) t += lpart[(size_t)g * NROWS + row];
        s += LN2f * log2f(t) - INVT * diag[row];
    }
    for (int m = 1; m < 64; m <<= 1) s += __shfl_xor(s, m, 64);
    int wave = threadIdx.x >> 6, lane = threadIdx.x & 63;
    if (lane == 0) sm[wave] = s;
    __syncthreads();
    if (threadIdx.x == 0) {
        float tot = sm[0] + sm[1] + sm[2] + sm[3];
        atomicAdd(out, tot * (1.0f / NROWS));
    }
}

extern "C" void kernel_launch(void* const* d_in, const int* in_sizes, int n_in,
                              void* d_out, int out_size, void* d_ws, size_t ws_size,
                              hipStream_t stream) {
    const float* fl = (const float*)d_in[0];
    const float* fg = (const float*)d_in[1];
    float* out = (float*)d_out;

    char* ws = (char*)d_ws;
    unsigned short* A = (unsigned short*)ws;                       // 16384*256*2 = 8 MB
    unsigned short* B = A + (size_t)NROWS * DIM;                   // 8 MB
    float* diag  = (float*)(ws + 2 * (size_t)NROWS * DIM * 2);     // 64 KB
    float* lpart = diag + NROWS;                                   // SEGS*N*4 = 512 KB

    norm_diag_kernel<<<NROWS / 4, 256, 0, stream>>>(fl, fg, A, B, diag, out);
    sim_lse_kernel<<<dim3(SEGS, NROWS / 256), 256, 0, stream>>>(A, B, lpart);
    reduce_kernel<<<32, 256, 0, stream>>>(lpart, diag, out);
}

// Round 5
// 170.351 us; speedup vs baseline: 2.6648x; 1.2610x over previous
//
#include <hip/hip_runtime.h>
#include <hip/hip_bf16.h>

#define NROWS 16384
#define DIM   256
#define SEGS  8
#define BN    64
#define NT    ((NROWS / SEGS) / BN)   // 32 column tiles per block
#define INVT  14.285714285714286f
#define C1f   20.60992915555662f   // log2(e)/0.07 ; A is pre-scaled by this
#define LN2f  0.6931471805599453f

typedef __attribute__((ext_vector_type(8)))  int   int8v;    // fp8 A/B fragment (32 bytes)
typedef __attribute__((ext_vector_type(16))) float f32x16;   // 32x32 MFMA accumulator

#define SCALE1 0x7F7F7F7F   // E8M0 = 1.0 in every byte (opsel-proof)

// Kernel 1: L2-normalize both feature sets (fp32); emit fp8 e4m3 A (scaled by C1)
// and fp8 B (unscaled), plus the exact fp32 diagonal. One wave per row.
__global__ __launch_bounds__(256) void norm_diag_kernel(
    const float* __restrict__ fl, const float* __restrict__ fg,
    unsigned char* __restrict__ A, unsigned char* __restrict__ B,
    float* __restrict__ diag, float* __restrict__ out)
{
    int tid  = threadIdx.x;
    int wave = tid >> 6, lane = tid & 63;
    int row  = blockIdx.x * 4 + wave;
    if (blockIdx.x == 0 && tid == 0) out[0] = 0.0f;   // zero accumulator for final atomicAdd

    float4 xl = ((const float4*)(fl + (size_t)row * DIM))[lane];
    float4 xg = ((const float4*)(fg + (size_t)row * DIM))[lane];
    float ssl = xl.x*xl.x + xl.y*xl.y + xl.z*xl.z + xl.w*xl.w;
    float ssg = xg.x*xg.x + xg.y*xg.y + xg.z*xg.z + xg.w*xg.w;
    for (int m = 1; m < 64; m <<= 1) {
        ssl += __shfl_xor(ssl, m, 64);
        ssg += __shfl_xor(ssg, m, 64);
    }
    float il = 1.0f / fmaxf(sqrtf(ssl), 1e-12f);
    float ig = 1.0f / fmaxf(sqrtf(ssg), 1e-12f);
    float nl0 = xl.x*il, nl1 = xl.y*il, nl2 = xl.z*il, nl3 = xl.w*il;
    float ng0 = xg.x*ig, ng1 = xg.y*ig, ng2 = xg.z*ig, ng3 = xg.w*ig;

    // Pack 4 values -> 1 int of fp8 e4m3 bytes (HW cvt, OCP on gfx950)
    int pa = __builtin_amdgcn_cvt_pk_fp8_f32(nl0 * C1f, nl1 * C1f, 0, false);
    pa     = __builtin_amdgcn_cvt_pk_fp8_f32(nl2 * C1f, nl3 * C1f, pa, true);
    int pb = __builtin_amdgcn_cvt_pk_fp8_f32(ng0, ng1, 0, false);
    pb     = __builtin_amdgcn_cvt_pk_fp8_f32(ng2, ng3, pb, true);
    ((int*)(A + (size_t)row * DIM))[lane] = pa;
    ((int*)(B + (size_t)row * DIM))[lane] = pb;

    float d = nl0*ng0 + nl1*ng1 + nl2*ng2 + nl3*ng3;   // exact fp32 diagonal
    for (int m = 1; m < 64; m <<= 1) d += __shfl_xor(d, m, 64);
    if (lane == 0) diag[row] = d;
}

// Kernel 2: fused sim-tile GEMM + fixed-max sumexp, MX-fp8 32x32x64 (scales = 1.0).
// Block = 4 waves = 256 rows; wave tile = 64 rows x 64 cols (2 row-sets x 2 col-sets).
// A frags register-resident (64 VGPRs); B tile (16 KB) double-buffered in LDS.
// LDS 16B-chunk layout: phys = kc*64 + (col ^ (kc&7)) -> conflict-free R/W (R4-verified scheme).
// acc = C1*dot directly (A pre-scaled); kk=0 MFMA takes C=Z (hoisted zeros) to skip acc init.
__global__ __launch_bounds__(256, 2) void sim_lse_kernel(
    const unsigned char* __restrict__ A, const unsigned char* __restrict__ B,
    float* __restrict__ lpart)
{
    __shared__ __align__(16) unsigned char bt[2 * BN * DIM];   // 2 x 16 KB double buffer

    int tid  = threadIdx.x;
    int lane = tid & 63;
    int l31  = lane & 31, half = lane >> 5;
    int wave = tid >> 6;
    int rowBase = blockIdx.y * 256 + wave * 64;

    // Staging map: 1024 16B chunks / 256 threads = 4 each; chunk i -> col=i>>4, kc=i&15
    int scol[4], skc[4];
    unsigned sphys[4];
#pragma unroll
    for (int j = 0; j < 4; ++j) {
        int i = tid + j * 256;
        scol[j] = i >> 4;
        skc[j]  = i & 15;
        sphys[j] = (unsigned)(skc[j] * 64 + (scol[j] ^ (skc[j] & 7)));
    }

    // Preload A fragments: lane(l31,half) holds A[m=l31][k = kk*64 + half*32 + 0..31]
    int8v af[2][4];
#pragma unroll
    for (int s = 0; s < 2; ++s) {
        const unsigned char* ap = A + (size_t)(rowBase + s*32 + l31) * DIM + half * 32;
#pragma unroll
        for (int kk = 0; kk < 4; ++kk) {
            int4 lo = *(const int4*)(ap + kk * 64);
            int4 hi = *(const int4*)(ap + kk * 64 + 16);
            int8v v;
            v[0]=lo.x; v[1]=lo.y; v[2]=lo.z; v[3]=lo.w;
            v[4]=hi.x; v[5]=hi.y; v[6]=hi.z; v[7]=hi.w;
            af[s][kk] = v;
        }
    }

    f32x16 lv[2];
    f32x16 Z;
#pragma unroll
    for (int r = 0; r < 16; ++r) { lv[0][r] = 0.0f; lv[1][r] = 0.0f; Z[r] = 0.0f; }

    int col0seg = blockIdx.x * (NROWS / SEGS);

    // Prefetch tile 0 into registers
    int4 stg[4];
#pragma unroll
    for (int j = 0; j < 4; ++j)
        stg[j] = *(const int4*)(B + (size_t)(col0seg + scol[j]) * DIM + skc[j] * 16);

    for (int t = 0; t < NT; ++t) {
        unsigned bufo = (t & 1) ? (unsigned)(BN * DIM) : 0u;
#pragma unroll
        for (int j = 0; j < 4; ++j)
            *(int4*)&bt[bufo + sphys[j] * 16] = stg[j];
        __syncthreads();

        // Issue loads for tile t+1 after the barrier so they fly through compute
        if (t + 1 < NT) {
            int col0n = col0seg + (t + 1) * BN;
#pragma unroll
            for (int j = 0; j < 4; ++j)
                stg[j] = *(const int4*)(B + (size_t)(col0n + scol[j]) * DIM + skc[j] * 16);
        }

        f32x16 acc[2][2];
#pragma unroll
        for (int kk = 0; kk < 4; ++kk) {
            int8v bfr[2];
#pragma unroll
            for (int c = 0; c < 2; ++c) {
                int col = c * 32 + l31;
                int kcb = kk * 4 + half * 2;                 // first of two 16B chunks
                unsigned p0 = (unsigned)(kcb * 64 + (col ^ (kcb & 7)));
                unsigned p1 = (unsigned)((kcb + 1) * 64 + (col ^ ((kcb + 1) & 7)));
                int4 lo = *(const int4*)&bt[bufo + p0 * 16];
                int4 hi = *(const int4*)&bt[bufo + p1 * 16];
                int8v v;
                v[0]=lo.x; v[1]=lo.y; v[2]=lo.z; v[3]=lo.w;
                v[4]=hi.x; v[5]=hi.y; v[6]=hi.z; v[7]=hi.w;
                bfr[c] = v;
            }
#pragma unroll
            for (int c = 0; c < 2; ++c) {
                if (kk == 0) {
                    acc[0][c] = __builtin_amdgcn_mfma_scale_f32_32x32x64_f8f6f4(
                        af[0][0], bfr[c], Z, 0, 0, 0, SCALE1, 0, SCALE1);
                    acc[1][c] = __builtin_amdgcn_mfma_scale_f32_32x32x64_f8f6f4(
                        af[1][0], bfr[c], Z, 0, 0, 0, SCALE1, 0, SCALE1);
                } else {
                    acc[0][c] = __builtin_amdgcn_mfma_scale_f32_32x32x64_f8f6f4(
                        af[0][kk], bfr[c], acc[0][c], 0, 0, 0, SCALE1, 0, SCALE1);
                    acc[1][c] = __builtin_amdgcn_mfma_scale_f32_32x32x64_f8f6f4(
                        af[1][kk], bfr[c], acc[1][c], 0, 0, 0, SCALE1, 0, SCALE1);
                }
            }
        }
        __syncthreads();   // all waves done reading buf[t&1] before overwrite at t+2

        // Epilogue: acc = C1*dot; vector adds pack to v_pk_add_f32.
#pragma unroll
        for (int s = 0; s < 2; ++s) {
            f32x16 e;
#pragma unroll
            for (int r = 0; r < 16; ++r)
                e[r] = __builtin_amdgcn_exp2f(acc[s][0][r]) + __builtin_amdgcn_exp2f(acc[s][1][r]);
            lv[s] += e;
        }
    }

    // Sum across the 32 column-lanes (xor 1..16 stays within each 32-half)
#pragma unroll
    for (int s = 0; s < 2; ++s)
#pragma unroll
        for (int r = 0; r < 16; ++r) {
            float v = lv[s][r];
            v += __shfl_xor(v, 1, 64);
            v += __shfl_xor(v, 2, 64);
            v += __shfl_xor(v, 4, 64);
            v += __shfl_xor(v, 8, 64);
            v += __shfl_xor(v, 16, 64);
            lv[s][r] = v;
        }
    if (l31 == 0) {
#pragma unroll
        for (int s = 0; s < 2; ++s)
#pragma unroll
            for (int r = 0; r < 16; ++r) {
                int row = rowBase + s*32 + (r & 3) + 8*(r >> 2) + 4*half;
                lpart[(size_t)blockIdx.x * NROWS + row] = lv[s][r];
            }
    }
}

// Kernel 3: loss_i = -invT*diag_i + ln2*log2(sum_seg l_part), then mean via atomicAdd.
__global__ __launch_bounds__(256) void reduce_kernel(
    const float* __restrict__ lpart, const float* __restrict__ diag,
    float* __restrict__ out)
{
    __shared__ float sm[4];
    int gtid = blockIdx.x * 256 + threadIdx.x;
    float s = 0.0f;
    for (int row = gtid; row < NROWS; row += 32 * 256) {
        float t = 0.0f;
#pragma unroll
        for (int g = 0; g < SEGS; ++g) t += lpart[(size_t)g * NROWS + row];
        s += LN2f * log2f(t) - INVT * diag[row];
    }
    for (int m = 1; m < 64; m <<= 1) s += __shfl_xor(s, m, 64);
    int wave = threadIdx.x >> 6, lane = threadIdx.x & 63;
    if (lane == 0) sm[wave] = s;
    __syncthreads();
    if (threadIdx.x == 0) {
        float tot = sm[0] + sm[1] + sm[2] + sm[3];
        atomicAdd(out, tot * (1.0f / NROWS));
    }
}

extern "C" void kernel_launch(void* const* d_in, const int* in_sizes, int n_in,
                              void* d_out, int out_size, void* d_ws, size_t ws_size,
                              hipStream_t stream) {
    const float* fl = (const float*)d_in[0];
    const float* fg = (const float*)d_in[1];
    float* out = (float*)d_out;

    char* ws = (char*)d_ws;
    unsigned char* A = (unsigned char*)ws;                         // 16384*256 = 4 MB
    unsigned char* B = A + (size_t)NROWS * DIM;                    // 4 MB
    float* diag  = (float*)(ws + 2 * (size_t)NROWS * DIM);         // 64 KB
    float* lpart = diag + NROWS;                                   // SEGS*N*4 = 512 KB

    norm_diag_kernel<<<NROWS / 4, 256, 0, stream>>>(fl, fg, A, B, diag, out);
    sim_lse_kernel<<<dim3(SEGS, NROWS / 256), 256, 0, stream>>>(A, B, lpart);
    reduce_kernel<<<32, 256, 0, stream>>>(lpart, diag, out);
}

// Round 6
// 141.579 us; speedup vs baseline: 3.2063x; 1.2032x over previous
//
#include <hip/hip_runtime.h>
#include <hip/hip_bf16.h>

#define NROWS 16384
#define DIM   256
#define SEGS  8
#define BN    128                     // staged tile: 128 cols x 256 k (fp8) = 32 KB
#define NT    ((NROWS / SEGS) / BN)   // 16 tiles per block
#define INVT  14.285714285714286f
#define C1f   20.60992915555662f      // log2(e)/0.07 ; A is pre-scaled by this
#define LN2f  0.6931471805599453f

typedef __attribute__((ext_vector_type(8)))  int   int8v;    // fp8 A/B fragment (32 bytes)
typedef __attribute__((ext_vector_type(16))) float f32x16;   // 32x32 MFMA accumulator

#define SCALE1 0x7F7F7F7F   // E8M0 = 1.0 in every byte (opsel-proof)

// Kernel 1: L2-normalize both feature sets (fp32); emit fp8 e4m3 A (row-major,
// scaled by C1) and fp8 B in the sim_lse staging/swizzle layout, plus the exact
// fp32 diagonal. One wave per row.
// B layout (16B chunks): chunk(col,kcb) = (col>>7)*2048 + ((col>>6)&1)*1024
//                                        + kcb*64 + ((col&63) ^ (kcb&7))
__global__ __launch_bounds__(256) void norm_diag_kernel(
    const float* __restrict__ fl, const float* __restrict__ fg,
    unsigned char* __restrict__ A, unsigned char* __restrict__ B,
    float* __restrict__ diag, float* __restrict__ out)
{
    int tid  = threadIdx.x;
    int wave = tid >> 6, lane = tid & 63;
    int row  = blockIdx.x * 4 + wave;
    if (blockIdx.x == 0 && tid == 0) out[0] = 0.0f;   // zero accumulator for final atomicAdd

    float4 xl = ((const float4*)(fl + (size_t)row * DIM))[lane];
    float4 xg = ((const float4*)(fg + (size_t)row * DIM))[lane];
    float ssl = xl.x*xl.x + xl.y*xl.y + xl.z*xl.z + xl.w*xl.w;
    float ssg = xg.x*xg.x + xg.y*xg.y + xg.z*xg.z + xg.w*xg.w;
    for (int m = 1; m < 64; m <<= 1) {
        ssl += __shfl_xor(ssl, m, 64);
        ssg += __shfl_xor(ssg, m, 64);
    }
    float il = 1.0f / fmaxf(sqrtf(ssl), 1e-12f);
    float ig = 1.0f / fmaxf(sqrtf(ssg), 1e-12f);
    float nl0 = xl.x*il, nl1 = xl.y*il, nl2 = xl.z*il, nl3 = xl.w*il;
    float ng0 = xg.x*ig, ng1 = xg.y*ig, ng2 = xg.z*ig, ng3 = xg.w*ig;

    // Pack 4 values -> 1 int of fp8 e4m3 bytes (HW cvt, OCP on gfx950)
    int pa = __builtin_amdgcn_cvt_pk_fp8_f32(nl0 * C1f, nl1 * C1f, 0, false);
    pa     = __builtin_amdgcn_cvt_pk_fp8_f32(nl2 * C1f, nl3 * C1f, pa, true);
    int pb = __builtin_amdgcn_cvt_pk_fp8_f32(ng0, ng1, 0, false);
    pb     = __builtin_amdgcn_cvt_pk_fp8_f32(ng2, ng3, pb, true);
    ((int*)(A + (size_t)row * DIM))[lane] = pa;   // A row-major

    // B swizzled: lane holds bytes [lane*4, lane*4+4) of this row(=col)
    {
        int kcb = lane >> 2;          // 16B chunk along K (0..15)
        int b4  = lane & 3;           // dword within chunk
        int c64 = row & 63;
        unsigned chunk = (unsigned)((row >> 7) * 2048 + ((row >> 6) & 1) * 1024
                                    + kcb * 64 + (c64 ^ (kcb & 7)));
        ((int*)B)[chunk * 4 + b4] = pb;
    }

    float d = nl0*ng0 + nl1*ng1 + nl2*ng2 + nl3*ng3;   // exact fp32 diagonal
    for (int m = 1; m < 64; m <<= 1) d += __shfl_xor(d, m, 64);
    if (lane == 0) diag[row] = d;
}

// Kernel 2: fused sim-tile GEMM + fixed-max sumexp, MX-fp8 32x32x64 (scales = 1.0).
// Block = 4 waves = 256 rows; staged tile = 128 cols, computed as two 64-col passes
// (wave tile 64x64 per pass, acc regs reused). Single barrier per tile:
//   sync -> issue global_load_lds DMA for tile t+1 -> compute tile t.
// Prefetch DMA stays in flight across the entire tile-t compute; the vmcnt drain
// at the next barrier finds it already complete (the m97-stall fix).
__global__ __launch_bounds__(256, 2) void sim_lse_kernel(
    const unsigned char* __restrict__ A, const unsigned char* __restrict__ B,
    float* __restrict__ lpart)
{
    __shared__ __align__(16) unsigned char bt[2 * BN * DIM];   // 2 x 32 KB double buffer

    int tid  = threadIdx.x;
    int lane = tid & 63;
    int l31  = lane & 31, half = lane >> 5;
    int wave = tid >> 6;
    int rowBase = blockIdx.y * 256 + wave * 64;

    // Preload A fragments: lane(l31,half) holds A[m=l31][k = kk*64 + half*32 + 0..31]
    int8v af[2][4];
#pragma unroll
    for (int s = 0; s < 2; ++s) {
        const unsigned char* ap = A + (size_t)(rowBase + s*32 + l31) * DIM + half * 32;
#pragma unroll
        for (int kk = 0; kk < 4; ++kk) {
            int4 lo = *(const int4*)(ap + kk * 64);
            int4 hi = *(const int4*)(ap + kk * 64 + 16);
            int8v v;
            v[0]=lo.x; v[1]=lo.y; v[2]=lo.z; v[3]=lo.w;
            v[4]=hi.x; v[5]=hi.y; v[6]=hi.z; v[7]=hi.w;
            af[s][kk] = v;
        }
    }

    f32x16 lv[2];
    f32x16 Z;
#pragma unroll
    for (int r = 0; r < 16; ++r) { lv[0][r] = 0.0f; lv[1][r] = 0.0f; Z[r] = 0.0f; }

    int T0 = blockIdx.x * NT;   // first 128-col tile of this segment

    // DMA staging: tile T -> buf. 2048 16B chunks; wave w moves chunks
    // [w*512 + j*64 + lane], j=0..7. Global layout == LDS layout (pre-swizzled).
    auto stage = [&](int T, unsigned bufo) {
        const unsigned char* g = B + (size_t)T * (BN * DIM) + (wave * 512 + lane) * 16;
        unsigned lo = bufo + (unsigned)(wave * 512) * 16;
#pragma unroll
        for (int j = 0; j < 8; ++j) {
            __builtin_amdgcn_global_load_lds(
                (const __attribute__((address_space(1))) unsigned int*)(g + j * 1024),
                (__attribute__((address_space(3))) unsigned int*)&bt[lo + j * 1024],
                16, 0, 0);
        }
    };

    stage(T0, 0);   // prologue: tile 0 in flight

    for (int t = 0; t < NT; ++t) {
        unsigned bufo = (t & 1) ? (unsigned)(BN * DIM) : 0u;
        __syncthreads();   // drains own tile-t DMA (in flight for a full tile), syncs waves

        if (t + 1 < NT)
            stage(T0 + t + 1, (t & 1) ? 0u : (unsigned)(BN * DIM));

        // Two 64-col passes over the staged 128-col tile
#pragma unroll
        for (int p = 0; p < 2; ++p) {
            unsigned subo = bufo + (unsigned)p * 16384;
            f32x16 acc[2][2];
#pragma unroll
            for (int kk = 0; kk < 4; ++kk) {
                int8v bfr[2];
#pragma unroll
                for (int c = 0; c < 2; ++c) {
                    int col = c * 32 + l31;
                    int kcb = kk * 4 + half * 2;                 // first of two 16B chunks
                    unsigned p0 = (unsigned)(kcb * 64 + (col ^ (kcb & 7)));
                    unsigned p1 = (unsigned)((kcb + 1) * 64 + (col ^ ((kcb + 1) & 7)));
                    int4 lo = *(const int4*)&bt[subo + p0 * 16];
                    int4 hi = *(const int4*)&bt[subo + p1 * 16];
                    int8v v;
                    v[0]=lo.x; v[1]=lo.y; v[2]=lo.z; v[3]=lo.w;
                    v[4]=hi.x; v[5]=hi.y; v[6]=hi.z; v[7]=hi.w;
                    bfr[c] = v;
                }
#pragma unroll
                for (int c = 0; c < 2; ++c) {
                    if (kk == 0) {
                        acc[0][c] = __builtin_amdgcn_mfma_scale_f32_32x32x64_f8f6f4(
                            af[0][0], bfr[c], Z, 0, 0, 0, SCALE1, 0, SCALE1);
                        acc[1][c] = __builtin_amdgcn_mfma_scale_f32_32x32x64_f8f6f4(
                            af[1][0], bfr[c], Z, 0, 0, 0, SCALE1, 0, SCALE1);
                    } else {
                        acc[0][c] = __builtin_amdgcn_mfma_scale_f32_32x32x64_f8f6f4(
                            af[0][kk], bfr[c], acc[0][c], 0, 0, 0, SCALE1, 0, SCALE1);
                        acc[1][c] = __builtin_amdgcn_mfma_scale_f32_32x32x64_f8f6f4(
                            af[1][kk], bfr[c], acc[1][c], 0, 0, 0, SCALE1, 0, SCALE1);
                    }
                }
            }
            // Epilogue: acc = C1*dot; exp2 and accumulate
#pragma unroll
            for (int s = 0; s < 2; ++s) {
                f32x16 e;
#pragma unroll
                for (int r = 0; r < 16; ++r)
                    e[r] = __builtin_amdgcn_exp2f(acc[s][0][r]) + __builtin_amdgcn_exp2f(acc[s][1][r]);
                lv[s] += e;
            }
        }
    }

    // Sum across the 32 column-lanes (xor 1..16 stays within each 32-half)
#pragma unroll
    for (int s = 0; s < 2; ++s)
#pragma unroll
        for (int r = 0; r < 16; ++r) {
            float v = lv[s][r];
            v += __shfl_xor(v, 1, 64);
            v += __shfl_xor(v, 2, 64);
            v += __shfl_xor(v, 4, 64);
            v += __shfl_xor(v, 8, 64);
            v += __shfl_xor(v, 16, 64);
            lv[s][r] = v;
        }
    if (l31 == 0) {
#pragma unroll
        for (int s = 0; s < 2; ++s)
#pragma unroll
            for (int r = 0; r < 16; ++r) {
                int row = rowBase + s*32 + (r & 3) + 8*(r >> 2) + 4*half;
                lpart[(size_t)blockIdx.x * NROWS + row] = lv[s][r];
            }
    }
}

// Kernel 3: loss_i = -invT*diag_i + ln2*log2(sum_seg l_part), then mean via atomicAdd.
__global__ __launch_bounds__(256) void reduce_kernel(
    const float* __restrict__ lpart, const float* __restrict__ diag,
    float* __restrict__ out)
{
    __shared__ float sm[4];
    int gtid = blockIdx.x * 256 + threadIdx.x;
    float s = 0.0f;
    for (int row = gtid; row < NROWS; row += 32 * 256) {
        float t = 0.0f;
#pragma unroll
        for (int g = 0; g < SEGS; ++g) t += lpart[(size_t)g * NROWS + row];
        s += LN2f * log2f(t) - INVT * diag[row];
    }
    for (int m = 1; m < 64; m <<= 1) s += __shfl_xor(s, m, 64);
    int wave = threadIdx.x >> 6, lane = threadIdx.x & 63;
    if (lane == 0) sm[wave] = s;
    __syncthreads();
    if (threadIdx.x == 0) {
        float tot = sm[0] + sm[1] + sm[2] + sm[3];
        atomicAdd(out, tot * (1.0f / NROWS));
    }
}

extern "C" void kernel_launch(void* const* d_in, const int* in_sizes, int n_in,
                              void* d_out, int out_size, void* d_ws, size_t ws_size,
                              hipStream_t stream) {
    const float* fl = (const float*)d_in[0];
    const float* fg = (const float*)d_in[1];
    float* out = (float*)d_out;

    char* ws = (char*)d_ws;
    unsigned char* A = (unsigned char*)ws;                         // 16384*256 = 4 MB
    unsigned char* B = A + (size_t)NROWS * DIM;                    // 4 MB (swizzled)
    float* diag  = (float*)(ws + 2 * (size_t)NROWS * DIM);         // 64 KB
    float* lpart = diag + NROWS;                                   // SEGS*N*4 = 512 KB

    norm_diag_kernel<<<NROWS / 4, 256, 0, stream>>>(fl, fg, A, B, diag, out);
    sim_lse_kernel<<<dim3(SEGS, NROWS / 256), 256, 0, stream>>>(A, B, lpart);
    reduce_kernel<<<32, 256, 0, stream>>>(lpart, diag, out);
}